// Round 11
// baseline (273.790 us; speedup 1.0000x reference)
//
#include <hip/hip_runtime.h>
#include <hip/hip_bf16.h>
#include <cstdint>

// SpatialAttentionModule: x[4,256,64,64] fp32; q=Wq x, k=Wk x, v=Wv x (1x1 conv);
// energy = q^T k per batch (N=4096), softmax over j, out = gamma*(v@attn^T) + x.
//
// Round-10 (fix of R10 compile error: legacy K=16 MFMA builtin is spelled
// __builtin_amdgcn_mfma_f32_16x16x16f16, no underscore before f16):
// k_attn LDS-traffic halving. R8 measured: total 251, k_attn 140 (unchanged),
// prep+overhead ~111us nearly invariant across 4 different prep
// implementations -> ~100us is fixed per-iteration overhead; k_attn is the
// only reducible term. k_attn is LDS-BW-bound (~82% LDS-pipe busy: 264 b128
// reads + 64 DMA writes + 610 conflict cyc per tile) due to 4x K/V re-read
// (1 LDS read per MFMA, 16-query waves). Fix: 32-query waves x 16-key
// j-quarters (8 waves = 2 wq x 4 wj):
//  - S^T: 16x16x32, each K-fragment read feeds TWO MFMAs (i-subtiles it=0,1)
//  - PV: 16x16x16 (k = 16 = j-quarter); V A-frags are 8B (b64) reads
//  - P: ZERO LDS -- S^T C-layout (row=quad*4+reg) == 16x16x16 B k-layout
//    (k=quad*4+j), so P = in-lane cvt of own S regs
//  - end merge: 4-way over wj states, 2 ct-rounds through retired K/V LDS
// Per tile: K 64 b128 + V 128 b64 + DMA 64 (~2100 cyc) vs ~4300 before.
// k_cast_w / k_qkv byte-identical to R8 (delta attribution).
// MFMA layouts (HW-verified, learn_hip m89/m91, dtype-independent):
//   16x16x32: A[m=lane&15][k=quad*8+j], B[k=quad*8+j][n=lane&15],
//             C/D: col=lane&15, row=quad*4+reg.
//   16x16x16: A[m=lane&15][k=quad*4+j], B[k=quad*4+j][n=lane&15], C/D same.

#define C_DIM 256
#define N_DIM 4096
#define B_DIM 4

typedef _Float16 f16;
typedef f16 f16x8 __attribute__((ext_vector_type(8)));
typedef f16 f16x4 __attribute__((ext_vector_type(4)));
typedef float f32x4 __attribute__((ext_vector_type(4)));

__device__ __forceinline__ void dma16(const f16* g, f16* l) {
  __builtin_amdgcn_global_load_lds(
      (const __attribute__((address_space(1))) unsigned int*)g,
      (__attribute__((address_space(3))) unsigned int*)l, 16, 0, 0);
}

// ---------------- prep: cast 3 weight matrices -> fp16 [3*256][256] ----------------
__global__ __launch_bounds__(256) void k_cast_w(const float* __restrict__ Wq,
                                                const float* __restrict__ Wk,
                                                const float* __restrict__ Wv,
                                                f16* __restrict__ Wh) {
  int i = blockIdx.x * 256 + threadIdx.x;          // 0 .. 3*65536-1
  int sel = i >> 16, j = i & 65535;
  const float* s = (sel == 0) ? Wq : (sel == 1) ? Wk : Wv;
  Wh[i] = (f16)s[j];
}

// ---------------- fused QKV projection (byte-identical to R8) ----------------
__global__ __launch_bounds__(512) void k_qkv(const float* __restrict__ x,
                                             const f16* __restrict__ Wh,
                                             const float* __restrict__ bq,
                                             const float* __restrict__ bk,
                                             const float* __restrict__ bv,
                                             f16* __restrict__ Qh,
                                             f16* __restrict__ Kh,
                                             f16* __restrict__ Vh) {
  __shared__ __align__(16) f16 xt[64 * 256];   // 32 KiB
  const int b = blockIdx.y, n0 = blockIdx.x * 64;
  const int tid = threadIdx.x;
  const int w = tid >> 6, lane = tid & 63;
  const int quad = lane >> 4, li = lane & 15;
  const int gt = w & 3, role = w >> 2;

  // ---- stage x tile (fp32 -> f16, swizzled) ----
  {
    const float* xb = x + (size_t)b * C_DIM * N_DIM + n0;
#pragma unroll
    for (int cg = 0; cg < 4; cg++) {
      f16x8 v;
#pragma unroll
      for (int j = 0; j < 8; j++) {
        int c = w * 32 + cg * 8 + j;
        v[j] = (f16)xb[(size_t)c * N_DIM + lane];
      }
      int chunk = w * 4 + cg;
      int slot = chunk ^ (lane & 7);
      *(f16x8*)(&xt[lane * 256 + slot * 8]) = v;
    }
  }
  __syncthreads();

  // ---- x fragments (shared by A- and B-roles) ----
  int xsl[8];
#pragma unroll
  for (int kf = 0; kf < 8; kf++) xsl[kf] = ((kf * 4 + quad) ^ (li & 7)) << 3;
  f16x8 xf[8];
  {
    const f16* xrow = xt + (gt * 16 + li) * 256;
#pragma unroll
    for (int kf = 0; kf < 8; kf++) xf[kf] = *(const f16x8*)(xrow + xsl[kf]);
  }

  // ---- Q or K: out[g][o], D rows = o ----
  {
    const f16* W = Wh + (size_t)role * 65536;
    const float* bias = role ? bk : bq;
    f16* out = role ? Kh : Qh;
    const size_t grow = (size_t)(b * N_DIM + n0 + gt * 16 + li) * C_DIM;
    for (int ot = 0; ot < 16; ot++) {
      f32x4 acc = {0.f, 0.f, 0.f, 0.f};
      const f16* wrow = W + (size_t)(ot * 16 + li) * C_DIM + quad * 8;
#pragma unroll
      for (int kf = 0; kf < 8; kf++) {
        f16x8 wf = *(const f16x8*)(wrow + kf * 32);
        acc = __builtin_amdgcn_mfma_f32_16x16x32_f16(wf, xf[kf], acc, 0, 0, 0);
      }
      const int o0 = ot * 16 + quad * 4;
      f16x4 st = {(f16)(acc[0] + bias[o0]), (f16)(acc[1] + bias[o0 + 1]),
                  (f16)(acc[2] + bias[o0 + 2]), (f16)(acc[3] + bias[o0 + 3])};
      *(f16x4*)(out + grow + o0) = st;
    }
  }

  // ---- V half: out[o][j], D rows = j ----
  {
    const f16* W = Wh + (size_t)2 * 65536;
#pragma unroll
    for (int ot8 = 0; ot8 < 8; ot8++) {
      const int ot = role * 8 + ot8;
      f32x4 acc = {0.f, 0.f, 0.f, 0.f};
      const f16* wrow = W + (size_t)(ot * 16 + li) * C_DIM + quad * 8;
#pragma unroll
      for (int kf = 0; kf < 8; kf++) {
        f16x8 wf = *(const f16x8*)(wrow + kf * 32);
        acc = __builtin_amdgcn_mfma_f32_16x16x32_f16(xf[kf], wf, acc, 0, 0, 0);
      }
      const float bb = bv[ot * 16 + li];
      f16x4 st = {(f16)(acc[0] + bb), (f16)(acc[1] + bb),
                  (f16)(acc[2] + bb), (f16)(acc[3] + bb)};
      *(f16x4*)(Vh + (size_t)(b * C_DIM + ot * 16 + li) * N_DIM +
                n0 + gt * 16 + quad * 4) = st;
    }
  }
}

// ---------------- fused attention (32q-wave x 16j-quarter) ----------------
// grid (64,4): 64-query block, batch. 8 waves: wq=w&1 (32 query cols, two
// 16-col subtiles it=0,1), wj=w>>1 (j-quarter of 16 keys per 64-key tile).
// JT=64 keys/tile, NT=64 tiles. DMA staging identical to R6/R8 (same LDS
// layouts, same XOR chunk swizzle):
//   K: [64 rows][256], row r: 16B slot s holds global chunk s^(r&7).
//   V: [256 rows][64], row c: slot s holds chunk s^(c&7).
// Reads: K A-frag rows wj*16+li, slot ((kf*4+quad)^(li&7)) -> b128, 2 MFMAs
//   each. V A-frag (16x16x16): row ct*16+li, j = wj*16+quad*4+0..3 ->
//   swizzled chunk (wj*2+(quad>>1))^(li&7), half (quad&1) -> b64.
// P: in registers only (C row=quad*4+reg == B k=quad*4+j).
// End: 4-way wj-state merge in 2 ct-rounds via retired K/V LDS (f32 view):
//   acc slot per upper wave uid=wq*3+wj-1: [32 i][132] f32; ML at 25344.
#define JT 64
#define NT (N_DIM / JT)
#define K0_OFF 0
#define K1_OFF 16384
#define V0_OFF 32768
#define V1_OFF 49152
#define SMEM_F16 65536        // 131072 B
#define MRG_SLOT 4224         // f32 per upper-wave slot (32 i * 132)
#define MRG_ISTR 132          // f32 i-row stride
#define ML_OFF   25344        // 6*4224

__global__ __launch_bounds__(512, 2) void k_attn(const f16* __restrict__ Qh,
                                                 const f16* __restrict__ Kh,
                                                 const f16* __restrict__ Vh,
                                                 const float* __restrict__ x,
                                                 const float* __restrict__ gamma_p,
                                                 float* __restrict__ out) {
  __shared__ __align__(16) f16 smem[SMEM_F16];
  const int b = blockIdx.y;
  const int tid = threadIdx.x;
  const int w = tid >> 6, lane = tid & 63;
  const int wq = w & 1, wj = w >> 1;
  const int quad = lane >> 4, li = lane & 15;
  const int lw = li & 7;
  const int ibase = blockIdx.x * 64 + wq * 32;   // first of this wave's 32 q-cols

  // loop-invariant swizzled offsets (f16 units), static-indexed
  int ksl[8];
#pragma unroll
  for (int kf = 0; kf < 8; kf++) ksl[kf] = ((kf * 4 + quad) ^ lw) << 3;
  const int vofs = (((wj * 2 + (quad >> 1)) ^ lw) << 3) + (quad & 1) * 4;

  // Q fragments for both i-subtiles (B-operand of 16x16x32: n = query col)
  f16x8 qf0[8], qf1[8];
  {
    const f16* qrow0 = Qh + (size_t)(b * N_DIM + ibase + li) * C_DIM + quad * 8;
    const f16* qrow1 = qrow0 + (size_t)16 * C_DIM;
#pragma unroll
    for (int kf = 0; kf < 8; kf++) {
      qf0[kf] = *(const f16x8*)(qrow0 + kf * 32);
      qf1[kf] = *(const f16x8*)(qrow1 + kf * 32);
    }
  }
  const f16* Kb = Kh + (size_t)b * N_DIM * C_DIM;
  const f16* Vb = Vh + (size_t)b * C_DIM * N_DIM;

  const float LOG2E = 1.4426950408889634f;
  float m0 = -3.0e38f, l0 = 0.0f, m1 = -3.0e38f, l1 = 0.0f;
  f32x4 acc[16][2];
#pragma unroll
  for (int ct = 0; ct < 16; ct++) {
    acc[ct][0] = (f32x4){0.f, 0.f, 0.f, 0.f};
    acc[ct][1] = (f32x4){0.f, 0.f, 0.f, 0.f};
  }

  // prologue: DMA tile 0 -> buf0 (pre-swizzled global source chunks; same as R8)
  {
#pragma unroll
    for (int it = 0; it < 4; it++) {
      int p = w * 4 + it;
      int krsw = (2 * it + (lane >> 5)) & 7;     // (2p+(l>>5))&7, since 8w==0 mod 8
      dma16(Kb + (size_t)(2 * p + (lane >> 5)) * C_DIM + (((lane & 31) ^ krsw) * 8),
            smem + K0_OFF + p * 512);
      dma16(Vb + (size_t)(p * 8 + (lane >> 3)) * N_DIM + (((lane & 7) ^ (lane >> 3)) * 8),
            smem + V0_OFF + p * 512);
    }
  }
  __syncthreads();

  for (int t = 0; t < NT; t++) {
    const f16* Kc = smem + ((t & 1) ? K1_OFF : K0_OFF);
    const f16* Vc = smem + ((t & 1) ? V1_OFF : V0_OFF);

    // issue DMA for tile t+1 into the other buffer (drained at the barrier)
    if (t + 1 < NT) {
      f16* Kn = smem + ((t & 1) ? K0_OFF : K1_OFF);
      f16* Vn = smem + ((t & 1) ? V0_OFF : V1_OFF);
      const int jt = (t + 1) * JT;
      const f16* kg = Kb + (size_t)jt * C_DIM;
      const f16* vg = Vb + jt;
#pragma unroll
      for (int it = 0; it < 4; it++) {
        int p = w * 4 + it;
        int krsw = (2 * it + (lane >> 5)) & 7;
        dma16(kg + (size_t)(2 * p + (lane >> 5)) * C_DIM + (((lane & 31) ^ krsw) * 8),
              Kn + p * 512);
        dma16(vg + (size_t)(p * 8 + (lane >> 3)) * N_DIM + (((lane & 7) ^ (lane >> 3)) * 8),
              Vn + p * 512);
      }
    }

    // ---- S^T for this wave's j-quarter: rows j = wj*16 + (quad*4+reg),
    //      cols i = it*16 + li; one K-frag read feeds both it-MFMAs ----
    f32x4 s0 = {0.f, 0.f, 0.f, 0.f}, s1 = {0.f, 0.f, 0.f, 0.f};
    {
      const f16* krow = Kc + (wj * 16 + li) * 256;   // row&7 == li&7
#pragma unroll
      for (int kf = 0; kf < 8; kf++) {
        f16x8 kfr = *(const f16x8*)(krow + ksl[kf]);
        s0 = __builtin_amdgcn_mfma_f32_16x16x32_f16(kfr, qf0[kf], s0, 0, 0, 0);
        s1 = __builtin_amdgcn_mfma_f32_16x16x32_f16(kfr, qf1[kf], s1, 0, 0, 0);
      }
    }

    // ---- online softmax per i-col (state per it) ----
    float tm0 = fmaxf(fmaxf(s0[0], s0[1]), fmaxf(s0[2], s0[3]));
    float tm1 = fmaxf(fmaxf(s1[0], s1[1]), fmaxf(s1[2], s1[3]));
    tm0 = fmaxf(tm0, __shfl_xor(tm0, 16));
    tm0 = fmaxf(tm0, __shfl_xor(tm0, 32));
    tm1 = fmaxf(tm1, __shfl_xor(tm1, 16));
    tm1 = fmaxf(tm1, __shfl_xor(tm1, 32));
    float nm0 = fmaxf(m0, tm0), nm1 = fmaxf(m1, tm1);
    float a0 = exp2f((m0 - nm0) * LOG2E);
    float a1 = exp2f((m1 - nm1) * LOG2E);
    m0 = nm0; m1 = nm1;
    if (__any(a0 < 1.0f || a1 < 1.0f)) {   // wave-uniform skip when maxes unchanged
      l0 *= a0; l1 *= a1;
#pragma unroll
      for (int ct = 0; ct < 16; ct++) {
        acc[ct][0][0] *= a0; acc[ct][0][1] *= a0;
        acc[ct][0][2] *= a0; acc[ct][0][3] *= a0;
        acc[ct][1][0] *= a1; acc[ct][1][1] *= a1;
        acc[ct][1][2] *= a1; acc[ct][1][3] *= a1;
      }
    }
    // P stays in registers: C row (quad*4+r) == 16x16x16 B k (quad*4+j)
    float p00 = exp2f((s0[0] - m0) * LOG2E), p01 = exp2f((s0[1] - m0) * LOG2E);
    float p02 = exp2f((s0[2] - m0) * LOG2E), p03 = exp2f((s0[3] - m0) * LOG2E);
    float p10 = exp2f((s1[0] - m1) * LOG2E), p11 = exp2f((s1[1] - m1) * LOG2E);
    float p12 = exp2f((s1[2] - m1) * LOG2E), p13 = exp2f((s1[3] - m1) * LOG2E);
    l0 += (p00 + p01) + (p02 + p03);
    l1 += (p10 + p11) + (p12 + p13);
    f16x4 pf0 = {(f16)p00, (f16)p01, (f16)p02, (f16)p03};
    f16x4 pf1 = {(f16)p10, (f16)p11, (f16)p12, (f16)p13};

    // ---- PV: O^T[c][i] += V[c][j-quarter] P^T[j-quarter][i], 16x16x16 ----
#pragma unroll
    for (int ct = 0; ct < 16; ct++) {
      const f16* vrow = Vc + (ct * 16 + li) * 64;
      f16x4 va = *(const f16x4*)(vrow + vofs);
      acc[ct][0] = __builtin_amdgcn_mfma_f32_16x16x16f16(va, pf0, acc[ct][0], 0, 0, 0);
      acc[ct][1] = __builtin_amdgcn_mfma_f32_16x16x16f16(va, pf1, acc[ct][1], 0, 0, 0);
    }

    __syncthreads();   // waits readers of current bufs AND drains next-tile DMA
  }

  // ---- finalize l (cross-quad sum); 4-way wj merge in 2 ct-rounds ----
  l0 += __shfl_xor(l0, 16); l0 += __shfl_xor(l0, 32);
  l1 += __shfl_xor(l1, 16); l1 += __shfl_xor(l1, 32);

  float* mrg = (float*)smem;
  const int uid = wq * 3 + (wj - 1);     // valid for wj>0
  // ML + round-A partials
  if (wj != 0) {
    if (quad == 0)
      *(f32x4*)(mrg + ML_OFF + (uid * 16 + li) * 4) = (f32x4){m0, m1, l0, l1};
    float* base = mrg + uid * MRG_SLOT;
#pragma unroll
    for (int c8 = 0; c8 < 8; c8++) {
      *(f32x4*)(base + (li) * MRG_ISTR + c8 * 16 + quad * 4) = acc[c8][0];
      *(f32x4*)(base + (16 + li) * MRG_ISTR + c8 * 16 + quad * 4) = acc[c8][1];
    }
  }
  __syncthreads();

  float es0 = 0.f, es1 = 0.f, e0[3], e1[3], scale0 = 0.f, scale1 = 0.f;
  if (wj == 0) {
    f32x4 mlp[3];
#pragma unroll
    for (int k = 0; k < 3; k++)
      mlp[k] = *(const f32x4*)(mrg + ML_OFF + ((wq * 3 + k) * 16 + li) * 4);
    float M0 = fmaxf(fmaxf(m0, mlp[0][0]), fmaxf(mlp[1][0], mlp[2][0]));
    float M1 = fmaxf(fmaxf(m1, mlp[0][1]), fmaxf(mlp[1][1], mlp[2][1]));
    es0 = exp2f((m0 - M0) * LOG2E);
    es1 = exp2f((m1 - M1) * LOG2E);
    float L0 = es0 * l0, L1 = es1 * l1;
#pragma unroll
    for (int k = 0; k < 3; k++) {
      e0[k] = exp2f((mlp[k][0] - M0) * LOG2E);
      e1[k] = exp2f((mlp[k][1] - M1) * LOG2E);
      L0 += e0[k] * mlp[k][2];
      L1 += e1[k] * mlp[k][3];
    }
    const float g = gamma_p[0];
    scale0 = g / L0; scale1 = g / L1;
  }

  const float* xb = x + (size_t)b * C_DIM * N_DIM;
  float* ob = out + (size_t)b * C_DIM * N_DIM;
  const int icol0 = ibase + li, icol1 = ibase + 16 + li;

  // Round A: owner combines+stores ct 0..7
  if (wj == 0) {
#pragma unroll
    for (int c8 = 0; c8 < 8; c8++) {
      f32x4 v0 = acc[c8][0], v1 = acc[c8][1];
      v0 *= es0; v1 *= es1;
#pragma unroll
      for (int k = 0; k < 3; k++) {
        const float* base = mrg + (wq * 3 + k) * MRG_SLOT;
        f32x4 q0 = *(const f32x4*)(base + li * MRG_ISTR + c8 * 16 + quad * 4);
        f32x4 q1 = *(const f32x4*)(base + (16 + li) * MRG_ISTR + c8 * 16 + quad * 4);
        v0 += e0[k] * q0; v1 += e1[k] * q1;
      }
#pragma unroll
      for (int r = 0; r < 4; r++) {
        size_t off0 = (size_t)(c8 * 16 + quad * 4 + r) * N_DIM;
        ob[off0 + icol0] = v0[r] * scale0 + xb[off0 + icol0];
        ob[off0 + icol1] = v1[r] * scale1 + xb[off0 + icol1];
      }
    }
  }
  __syncthreads();

  // Round B: partials + combine for ct 8..15
  if (wj != 0) {
    float* base = mrg + uid * MRG_SLOT;
#pragma unroll
    for (int c8 = 0; c8 < 8; c8++) {
      *(f32x4*)(base + li * MRG_ISTR + c8 * 16 + quad * 4) = acc[8 + c8][0];
      *(f32x4*)(base + (16 + li) * MRG_ISTR + c8 * 16 + quad * 4) = acc[8 + c8][1];
    }
  }
  __syncthreads();
  if (wj == 0) {
#pragma unroll
    for (int c8 = 0; c8 < 8; c8++) {
      f32x4 v0 = acc[8 + c8][0], v1 = acc[8 + c8][1];
      v0 *= es0; v1 *= es1;
#pragma unroll
      for (int k = 0; k < 3; k++) {
        const float* base = mrg + (wq * 3 + k) * MRG_SLOT;
        f32x4 q0 = *(const f32x4*)(base + li * MRG_ISTR + c8 * 16 + quad * 4);
        f32x4 q1 = *(const f32x4*)(base + (16 + li) * MRG_ISTR + c8 * 16 + quad * 4);
        v0 += e0[k] * q0; v1 += e1[k] * q1;
      }
#pragma unroll
      for (int r = 0; r < 4; r++) {
        size_t off0 = (size_t)(128 + c8 * 16 + quad * 4 + r) * N_DIM;
        ob[off0 + icol0] = v0[r] * scale0 + xb[off0 + icol0];
        ob[off0 + icol1] = v1[r] * scale1 + xb[off0 + icol1];
      }
    }
  }
}

extern "C" void kernel_launch(void* const* d_in, const int* in_sizes, int n_in,
                              void* d_out, int out_size, void* d_ws, size_t ws_size,
                              hipStream_t stream) {
  const float* x     = (const float*)d_in[0];
  const float* Wq    = (const float*)d_in[1];
  const float* bq    = (const float*)d_in[2];
  const float* Wk    = (const float*)d_in[3];
  const float* bk    = (const float*)d_in[4];
  const float* Wv    = (const float*)d_in[5];
  const float* bv    = (const float*)d_in[6];
  const float* gamma = (const float*)d_in[7];
  float* out = (float*)d_out;

  // workspace: Qh 8MB | Kh 8MB | Vh 8MB | Wh 384KB  (~24.4 MB)
  char* ws = (char*)d_ws;
  f16* Qh = (f16*)(ws);
  f16* Kh = (f16*)(ws + (size_t)8  * 1024 * 1024);
  f16* Vh = (f16*)(ws + (size_t)16 * 1024 * 1024);
  f16* Wh = (f16*)(ws + (size_t)24 * 1024 * 1024);

  k_cast_w<<<dim3(768), 256, 0, stream>>>(Wq, Wk, Wv, Wh);
  k_qkv<<<dim3(64, 4), 512, 0, stream>>>(x, Wh, bq, bk, bv, Qh, Kh, Vh);
  k_attn<<<dim3(64, 4), 512, 0, stream>>>(Qh, Kh, Vh, x, gamma, out);
}